// Round 10
// baseline (708.795 us; speedup 1.0000x reference)
//
#include <hip/hip_runtime.h>

typedef _Float16 f16;
typedef _Float16 f16x8 __attribute__((ext_vector_type(8)));
typedef _Float16 f16x4 __attribute__((ext_vector_type(4)));
typedef float f32x4 __attribute__((ext_vector_type(4)));

#define BM 128
#define BN 128

__device__ __forceinline__ float fast_tanh(float x) {
    return 1.0f - 2.0f / (__expf(2.0f * x) + 1.0f);
}

// async 16B global->LDS: LDS dest = wave-uniform base + lane*16
__device__ __forceinline__ void ld16(const void* g, void* l) {
    __builtin_amdgcn_global_load_lds(
        (const __attribute__((address_space(1))) void*)g,
        (__attribute__((address_space(3))) void*)l, 16, 0, 0);
}

// ---------------- job-table GEMM ------------------------------------------
struct Job {
    const f16* A; const f16* B;
    f16* Cout; f16* CTout;
    const f16* Sadd;
    const float* wvec;
    float* logits;
    long sA, sB, sC, sCT, sS, sL;
    int lda, ldb, ldc, ldct, ldsa;
    int mode, swz, gxl, K;
};
struct JobPack { Job j[3]; int end0, end1; };

struct MegaArgs {
    JobPack pA, p2, p4;
    const float *s1, *s2, *W, *Wv, *Wq;
    f16 *s1b, *s2b, *WTb, *WvTb, *WqTb;
    float *logv, *logq, *out;
    const int *m1, *m2;
    const f16 *s1h, *s2h;
    const float *s1f, *s2f;
    const float *whv, *whq;
    int use_h;
    unsigned int* cnt;
};

// device-scope grid barrier: all `grid` blocks co-resident by construction.
__device__ __forceinline__ void gsync(unsigned int* cnt, unsigned int target) {
    __syncthreads();
    if (threadIdx.x == 0) {
        __threadfence();  // agent release: drain + L2 writeback
        __hip_atomic_fetch_add(cnt, 1u, __ATOMIC_ACQ_REL, __HIP_MEMORY_SCOPE_AGENT);
        while (__hip_atomic_load(cnt, __ATOMIC_ACQUIRE, __HIP_MEMORY_SCOPE_AGENT) < target)
            __builtin_amdgcn_s_sleep(8);
        __threadfence();  // agent acquire: invalidate stale lines
    }
    __syncthreads();
}

// ---- phase 0: converts + weight transposes + zero-init (vblock = prep bid)
__device__ __forceinline__ void prep_job(const MegaArgs& a, int bid) {
    int tid = threadIdx.x;
    if (bid < 32768) {
        int g = bid * 256 + tid;                  // [0, 8388608)
        const int F = 4194304;                    // float4 per tensor
        const float* src = (g < F) ? a.s1 : a.s2;
        f16* dst = (g < F) ? a.s1b : a.s2b;
        int i = (g < F) ? g : g - F;
        float4 v = ((const float4*)src)[i];
        f16x4 h = {(f16)v.x, (f16)v.y, (f16)v.z, (f16)v.w};
        *(f16x4*)(dst + 4L * i) = h;
    } else if (bid < 34816) {
        int t2 = (bid - 32768) * 256 + tid;       // [0, 524288)
        if (t2 < 262144) {                        // W [512x512] -> WT
            int c = t2 >> 9, r = t2 & 511;
            a.WTb[t2] = (f16)a.W[r * 512 + c];
        } else if (t2 < 393216) {                 // Wv [512x256] -> WvT
            int i = t2 - 262144;
            int c = i >> 9, r = i & 511;
            a.WvTb[i] = (f16)a.Wv[r * 256 + c];
        } else {                                  // Wq [512x256] -> WqT
            int i = t2 - 393216;
            int c = i >> 9, r = i & 511;
            a.WqTb[i] = (f16)a.Wq[r * 256 + c];
        }
    } else {
        int t3 = (bid - 34816) * 256 + tid;       // [0, 32768) float4
        float4 z = {0.f, 0.f, 0.f, 0.f};
        if (t3 < 16384) ((float4*)a.logv)[t3] = z;  // logv+logq (contiguous)
        else ((float4*)a.out)[t3 - 16384] = z;      // out
    }
}

// ---- GEMM phase body: NT GEMM, double-buffered LDS, raw s_barrier + vmcnt(4)
// swz >= 0: z-batched XCD cluster (tiles/z = 1<<swz share bid%8).
// swz == -2: single-batch XCD cluster: by = xcd*32+v.
// modes: 0 = f16 C; 1 = tanh -> C + staged C^T; 2 = C + staged C^T; 3 = logits.
__device__ __forceinline__ void gemm_job(const JobPack& jp, int bid, char* smem) {
    int ji = (bid < jp.end0) ? 0 : ((bid < jp.end1) ? 1 : 2);
    const Job J = jp.j[ji];
    int local = bid - ((ji == 0) ? 0 : ((ji == 1) ? jp.end0 : jp.end1));

    int bx, by, bz;
    if (J.swz >= 0) {
        int tg = local >> 3;
        bz = (local & 7) + 8 * (tg >> J.swz);
        int t = tg & ((1 << J.swz) - 1);
        bx = t & ((1 << J.gxl) - 1);
        by = t >> J.gxl;
    } else {  // -2: single batch
        bz = 0;
        int x = local & 7, u = local >> 3;
        bx = u >> 5;
        by = (x << 5) | (u & 31);
    }

    const f16* Ab = J.A + (long)bz * J.sA;
    const f16* Bb = J.B + (long)bz * J.sB;
    int m0 = by * BM;
    int n0 = bx * BN;
    int tid = threadIdx.x;
    int wave = tid >> 6, lane = tid & 63;
    int quad = lane >> 4, l16 = lane & 15;
    int wm = (wave >> 1) * 64, wn = (wave & 1) * 64;

    f16* T = (f16*)smem;

    f32x4 zero = {0.f, 0.f, 0.f, 0.f};
    f32x4 acc[4][4];
#pragma unroll
    for (int i = 0; i < 4; i++)
#pragma unroll
        for (int j = 0; j < 4; j++) acc[i][j] = zero;

    int lda = J.lda, ldb = J.ldb;
    auto stage = [&](int buf, int k0) {
        f16* As = (f16*)(smem + buf * 16384);
        f16* Bs = (f16*)(smem + buf * 16384 + 8192);
#pragma unroll
        for (int j = 0; j < 2; j++) {
            int rbase = wave * 32 + j * 16;
            int r = rbase + (lane >> 2);
            int sw = ((lane & 3) ^ ((r >> 1) & 3)) << 3;
            ld16(Ab + (long)(m0 + r) * lda + k0 + sw, As + rbase * 32);
            ld16(Bb + (long)(n0 + r) * ldb + k0 + sw, Bs + rbase * 32);
        }
    };

    const int NK = J.K >> 5;
    stage(0, 0);
    for (int ki = 0; ki < NK; ki++) {
        int cur = ki & 1;
        __builtin_amdgcn_s_barrier();           // buf[1-cur] readers done
        asm volatile("" ::: "memory");
        if (ki + 1 < NK) {
            stage(1 - cur, (ki + 1) << 5);
            __builtin_amdgcn_s_waitcnt(0xF74);  // vmcnt(4): tile-ki DMAs done
        } else {
            __builtin_amdgcn_s_waitcnt(0xF70);  // vmcnt(0)
        }
        __builtin_amdgcn_s_barrier();           // tile-ki visible to all
        asm volatile("" ::: "memory");

        const f16* As = (const f16*)(smem + cur * 16384);
        const f16* Bs = (const f16*)(smem + cur * 16384 + 8192);
        f16x8 af[4], bfr[4];
#pragma unroll
        for (int mt = 0; mt < 4; mt++) {
            int row = wm + mt * 16 + l16;
            af[mt] = *(const f16x8*)(As + row * 32 + ((quad ^ ((row >> 1) & 3)) << 3));
        }
#pragma unroll
        for (int nt = 0; nt < 4; nt++) {
            int row = wn + nt * 16 + l16;
            bfr[nt] = *(const f16x8*)(Bs + row * 32 + ((quad ^ ((row >> 1) & 3)) << 3));
        }
#pragma unroll
        for (int mt = 0; mt < 4; mt++)
#pragma unroll
            for (int nt = 0; nt < 4; nt++)
                acc[mt][nt] = __builtin_amdgcn_mfma_f32_16x16x32_f16(af[mt], bfr[nt], acc[mt][nt], 0, 0, 0);
        asm volatile("" ::: "memory");
    }

    int gmb = m0 + wm;
    int gnb = n0 + wn;

    if (J.mode == 3) {
        const f16* Sb = J.Sadd + (long)bz * J.sS;
        float* lg = J.logits + (long)bz * J.sL;
#pragma unroll
        for (int mt = 0; mt < 4; mt++) {
            int rowb = gmb + mt * 16 + quad * 4;
            float part[4] = {0.f, 0.f, 0.f, 0.f};
#pragma unroll
            for (int nt = 0; nt < 4; nt++) {
                int col = gnb + nt * 16 + l16;
                float w = J.wvec[col];
#pragma unroll
                for (int r = 0; r < 4; r++) {
                    float s = (float)Sb[(long)(rowb + r) * J.ldsa + col];
                    part[r] += fast_tanh(s + acc[mt][nt][r]) * w;
                }
            }
#pragma unroll
            for (int off = 1; off < 16; off <<= 1) {
#pragma unroll
                for (int r = 0; r < 4; r++) part[r] += __shfl_xor(part[r], off);
            }
            if (l16 == 0) {
#pragma unroll
                for (int r = 0; r < 4; r++) atomicAdd(&lg[rowb + r], part[r]);
            }
        }
    } else {
        // convert (and tanh for mode 1) ONCE into f16 regs; reuse for both stores
        f16x4 hreg[4][4];
#pragma unroll
        for (int mt = 0; mt < 4; mt++)
#pragma unroll
            for (int nt = 0; nt < 4; nt++) {
                float v0 = acc[mt][nt][0], v1 = acc[mt][nt][1];
                float v2 = acc[mt][nt][2], v3 = acc[mt][nt][3];
                if (J.mode == 1) {
                    v0 = fast_tanh(v0); v1 = fast_tanh(v1);
                    v2 = fast_tanh(v2); v3 = fast_tanh(v3);
                }
                f16x4 hv = {(f16)v0, (f16)v1, (f16)v2, (f16)v3};
                hreg[mt][nt] = hv;
            }

        f16* Cb = J.Cout + (long)bz * J.sC;
#pragma unroll
        for (int mt = 0; mt < 4; mt++) {
            int rowb = gmb + mt * 16 + quad * 4;
#pragma unroll
            for (int nt = 0; nt < 4; nt++) {
                int col = gnb + nt * 16 + l16;
#pragma unroll
                for (int r = 0; r < 4; r++)
                    Cb[(long)(rowb + r) * J.ldc + col] = hreg[mt][nt][r];
            }
        }

        if (J.mode == 1 || J.mode == 2) {
            // staged transpose through LDS -> coalesced CT stores
            long bb = (J.mode == 2) ? (m0 >> 9) : bz;
            int lr0  = (J.mode == 2) ? (m0 & 511) : m0;
            f16* CTb = J.CTout + bb * J.sCT;
#pragma unroll
            for (int h = 0; h < 2; h++) {
                __syncthreads();
                if ((wave & 1) == h) {
#pragma unroll
                    for (int mt = 0; mt < 4; mt++) {
                        int rloc = wm + mt * 16 + quad * 4;
#pragma unroll
                        for (int nt = 0; nt < 4; nt++) {
                            int cloc = nt * 16 + l16;
                            *(f16x4*)(T + cloc * 136 + rloc) = hreg[mt][nt];
                        }
                    }
                }
                __syncthreads();
#pragma unroll
                for (int i = 0; i < 4; i++) {
                    int id = tid + i * 256;
                    int c = id >> 4, r8 = (id & 15) * 8;
                    f16x8 v = *(const f16x8*)(T + c * 136 + r8);
                    *(f16x8*)(CTb + (long)(n0 + h * 64 + c) * J.ldct + lr0 + r8) = v;
                }
            }
        }
    }
    __syncthreads();  // LDS reuse safety across persistent vblock iterations
}

// ---- 256-thread block reduce over 512-wide data (2 elems/thread folded in)
__device__ __forceinline__ float red256(float v, float* red, bool is_max) {
    int tid = threadIdx.x;
#pragma unroll
    for (int off = 32; off >= 1; off >>= 1) {
        float o = __shfl_xor(v, off);
        v = is_max ? fmaxf(v, o) : (v + o);
    }
    if ((tid & 63) == 0) red[tid >> 6] = v;
    __syncthreads();
    float t = is_max ? fmaxf(fmaxf(red[0], red[1]), fmaxf(red[2], red[3]))
                     : (red[0] + red[1] + red[2] + red[3]);
    __syncthreads();
    return t;
}

// ---- gather phase: vblock v -> (b, which, zp of 8); 64 l's, 2 d's/thread
__device__ __forceinline__ void gather_job(const MegaArgs& a, int v, char* smem) {
    float* p = (float*)smem;
    float* red = (float*)(smem + 2048);
    int b = v >> 4, which = (v >> 3) & 1, zp = v & 7;
    const float* lg = (which ? a.logq : a.logv) + (long)b * 512;
    const int* mk = (which ? a.m2 : a.m1) + (long)b * 512;
    float* o = a.out + (long)which * 64 * 512 + (long)b * 512;
    int tid = threadIdx.x;
    __syncthreads();  // p[] reuse across vblock iterations
    float m0 = (float)mk[tid], m1f = (float)mk[tid + 256];
    float l0v = __hip_atomic_load(&lg[tid], __ATOMIC_RELAXED, __HIP_MEMORY_SCOPE_AGENT);
    float l1v = __hip_atomic_load(&lg[tid + 256], __ATOMIC_RELAXED, __HIP_MEMORY_SCOPE_AGENT);
    float x0 = l0v * m0, x1 = l1v * m1f;
    float mx = red256(fmaxf(x0, x1), red, true);
    float e0 = __expf(x0 - mx), e1 = __expf(x1 - mx);
    float S1 = red256(e0 + e1, red, false);
    float r0 = (e0 / S1) * m0, r1 = (e1 / S1) * m1f;
    float S2 = red256(r0 + r1, red, false);
    p[tid] = r0 / (S2 + 1e-13f);
    p[tid + 256] = r1 / (S2 + 1e-13f);
    __syncthreads();
    float a0 = 0.f, a1 = 0.f;
    int l0 = zp * 64;
    if (a.use_h) {
        const f16* S = (which ? a.s2h : a.s1h) + (long)b * 262144;
#pragma unroll 4
        for (int l = l0; l < l0 + 64; l++) {
            float pl = p[l];
            a0 += pl * (float)S[(long)l * 512 + tid];
            a1 += pl * (float)S[(long)l * 512 + tid + 256];
        }
    } else {
        const float* S = (which ? a.s2f : a.s1f) + (long)b * 262144;
#pragma unroll 4
        for (int l = l0; l < l0 + 64; l++) {
            float pl = p[l];
            a0 += pl * S[(long)l * 512 + tid];
            a1 += pl * S[(long)l * 512 + tid + 256];
        }
    }
    atomicAdd(&o[tid], a0);
    atomicAdd(&o[tid + 256], a1);
}

// ---- the persistent mega-kernel: 512 blocks (2/CU, guaranteed co-resident)
__global__ __launch_bounds__(256, 2) void mega(MegaArgs a) {
    __shared__ __align__(16) char smem[32768];
    const int G = gridDim.x;
    for (int v = blockIdx.x; v < 34944; v += G) prep_job(a, v);
    gsync(a.cnt, 1u * G);
    for (int v = blockIdx.x; v < 2048; v += G) gemm_job(a.pA, v, smem);
    gsync(a.cnt, 2u * G);
    for (int v = blockIdx.x; v < 1024; v += G) gemm_job(a.p2, v, smem);
    gsync(a.cnt, 3u * G);
    for (int v = blockIdx.x; v < 1024; v += G) gemm_job(a.p4, v, smem);
    gsync(a.cnt, 4u * G);
    for (int v = blockIdx.x; v < 1024; v += G) gather_job(a, v, smem);
}

extern "C" void kernel_launch(void* const* d_in, const int* in_sizes, int n_in,
                              void* d_out, int out_size, void* d_ws, size_t ws_size,
                              hipStream_t stream) {
    const float* s1  = (const float*)d_in[0];
    const float* s2  = (const float*)d_in[1];
    const int* mask1 = (const int*)d_in[2];
    const int* mask2 = (const int*)d_in[3];
    const float* W   = (const float*)d_in[4];
    const float* Wv  = (const float*)d_in[5];
    const float* Wq  = (const float*)d_in[6];
    const float* whv = (const float*)d_in[7];
    const float* whq = (const float*)d_in[8];
    float* out = (float*)d_out;

    const long Bn = 64, L = 512, D = 512, Aa = 256;
    char* ws = (char*)d_ws;
    size_t off = 0;
    auto alloc = [&](size_t bytes) -> char* {
        char* p = ws + off;
        off += (bytes + 255) & ~(size_t)255;
        return p;
    };
    f16* s1b   = (f16*)alloc(Bn * L * D * 2);
    f16* s2b   = (f16*)alloc(Bn * L * D * 2);
    f16* s1W   = (f16*)alloc(Bn * L * D * 2);
    f16* Cb    = (f16*)alloc(Bn * L * L * 2);
    f16* s1Wv  = (f16*)alloc(Bn * L * Aa * 2);
    f16* s1WvT = (f16*)alloc(Bn * L * Aa * 2);
    f16* s2Wq  = (f16*)alloc(Bn * L * Aa * 2);
    f16* s2WqT = (f16*)alloc(Bn * L * Aa * 2);
    f16* WTb   = (f16*)alloc(D * D * 2);
    f16* WvTb  = (f16*)alloc(D * Aa * 2);
    f16* WqTb  = (f16*)alloc(D * Aa * 2);
    float* logv = (float*)alloc(2 * Bn * L * 4);
    float* logq = logv + Bn * L;
    unsigned int* cnt = (unsigned int*)alloc(256);
    size_t base_off = off;
    f16* CTded = (f16*)alloc(Bn * L * L * 2);  // dedicated CT if it fits
    if (ws_size < base_off) return;
    int use_ded = (ws_size >= off) ? 1 : 0;
    f16* CTb = use_ded ? CTded : s1b;  // fallback: alias (then f32 gather)

    hipMemsetAsync(cnt, 0, 4, stream);

    MegaArgs a{};
    // packA: GEMM1 + GEMM3a + GEMM3b (2048 vblocks)
    {
        Job& j0 = a.pA.j[0];
        j0.A = s1b; j0.B = WTb; j0.Cout = s1W;
        j0.lda = 512; j0.ldb = 512; j0.ldc = 512; j0.K = 512;
        j0.mode = 0; j0.swz = -2; j0.gxl = 2;
        Job& j1 = a.pA.j[1];
        j1.A = s1b; j1.B = WvTb; j1.Cout = s1Wv; j1.CTout = s1WvT;
        j1.lda = 512; j1.ldb = 512; j1.ldc = 256; j1.ldct = 512; j1.sCT = L * Aa;
        j1.K = 512; j1.mode = 2; j1.swz = -2; j1.gxl = 1;
        Job& j2 = a.pA.j[2];
        j2.A = s2b; j2.B = WqTb; j2.Cout = s2Wq; j2.CTout = s2WqT;
        j2.lda = 512; j2.ldb = 512; j2.ldc = 256; j2.ldct = 512; j2.sCT = L * Aa;
        j2.K = 512; j2.mode = 2; j2.swz = -2; j2.gxl = 1;
        a.pA.end0 = 1024; a.pA.end1 = 1536;
    }
    // pack2: GEMM2 (1024 vblocks, XCD-clustered 16 tiles/z)
    {
        Job& j0 = a.p2.j[0];
        j0.A = s1W; j0.B = s2b; j0.Cout = Cb; j0.CTout = CTb;
        j0.lda = 512; j0.ldb = 512; j0.ldc = 512; j0.ldct = 512;
        j0.sA = L * D; j0.sB = L * D; j0.sC = L * L; j0.sCT = L * L;
        j0.K = 512; j0.mode = 1; j0.swz = 4; j0.gxl = 2;
        a.p2.end0 = 1024; a.p2.end1 = 1024;
    }
    // pack4: GEMM4a + GEMM4b (1024 vblocks, XCD-clustered 8 tiles/z)
    {
        Job& j0 = a.p4.j[0];
        j0.A = Cb; j0.B = s2WqT; j0.Sadd = s1Wv; j0.wvec = whv; j0.logits = logv;
        j0.lda = 512; j0.ldb = 512; j0.ldsa = 256;
        j0.sA = L * L; j0.sB = Aa * L; j0.sS = L * Aa; j0.sL = 512;
        j0.K = 512; j0.mode = 3; j0.swz = 3; j0.gxl = 1;
        Job& j1 = a.p4.j[1];
        j1.A = CTb; j1.B = s1WvT; j1.Sadd = s2Wq; j1.wvec = whq; j1.logits = logq;
        j1.lda = 512; j1.ldb = 512; j1.ldsa = 256;
        j1.sA = L * L; j1.sB = Aa * L; j1.sS = L * Aa; j1.sL = 512;
        j1.K = 512; j1.mode = 3; j1.swz = 3; j1.gxl = 1;
        a.p4.end0 = 512; a.p4.end1 = 1024;
    }
    a.s1 = s1; a.s2 = s2; a.W = W; a.Wv = Wv; a.Wq = Wq;
    a.s1b = s1b; a.s2b = s2b; a.WTb = WTb; a.WvTb = WvTb; a.WqTb = WqTb;
    a.logv = logv; a.logq = logq; a.out = out;
    a.m1 = mask1; a.m2 = mask2;
    a.s1h = s1b; a.s2h = s2b; a.s1f = s1; a.s2f = s2;
    a.whv = whv; a.whq = whq;
    a.use_h = use_ded;
    a.cnt = cnt;

    mega<<<dim3(512), dim3(256), 0, stream>>>(a);
}

// Round 11
// 311.432 us; speedup vs baseline: 2.2759x; 2.2759x over previous
//
#include <hip/hip_runtime.h>

typedef _Float16 f16;
typedef _Float16 f16x8 __attribute__((ext_vector_type(8)));
typedef _Float16 f16x4 __attribute__((ext_vector_type(4)));
typedef float f32x4 __attribute__((ext_vector_type(4)));

#define BM 64
#define BN 128

__device__ __forceinline__ float fast_tanh(float x) {
    return 1.0f - 2.0f / (__expf(2.0f * x) + 1.0f);
}

// async 16B global->LDS: LDS dest = wave-uniform base + lane*16
__device__ __forceinline__ void ld16(const void* g, void* l) {
    __builtin_amdgcn_global_load_lds(
        (const __attribute__((address_space(1))) void*)g,
        (__attribute__((address_space(3))) void*)l, 16, 0, 0);
}

// ---------------- prep: converts + weight transposes + zero-init ----------
__global__ __launch_bounds__(256) void prep(
    const float* __restrict__ s1, const float* __restrict__ s2,
    f16* __restrict__ s1b, f16* __restrict__ s2b,
    const float* __restrict__ W, const float* __restrict__ Wv,
    const float* __restrict__ Wq,
    f16* __restrict__ WTb, f16* __restrict__ WvTb, f16* __restrict__ WqTb,
    float* __restrict__ logv, float* __restrict__ out)
{
    int bid = blockIdx.x, tid = threadIdx.x;
    if (bid < 32768) {
        int g = bid * 256 + tid;                  // [0, 8388608)
        const int F = 4194304;                    // float4 per tensor
        const float* src = (g < F) ? s1 : s2;
        f16* dst = (g < F) ? s1b : s2b;
        int i = (g < F) ? g : g - F;
        float4 v = ((const float4*)src)[i];
        f16x4 h = {(f16)v.x, (f16)v.y, (f16)v.z, (f16)v.w};
        *(f16x4*)(dst + 4L * i) = h;
    } else if (bid < 34816) {
        int t2 = (bid - 32768) * 256 + tid;       // [0, 524288)
        if (t2 < 262144) {                        // W [512x512] -> WT
            int c = t2 >> 9, r = t2 & 511;
            WTb[t2] = (f16)W[r * 512 + c];
        } else if (t2 < 393216) {                 // Wv [512x256] -> WvT
            int i = t2 - 262144;
            int c = i >> 9, r = i & 511;
            WvTb[i] = (f16)Wv[r * 256 + c];
        } else {                                  // Wq [512x256] -> WqT
            int i = t2 - 393216;
            int c = i >> 9, r = i & 511;
            WqTb[i] = (f16)Wq[r * 256 + c];
        }
    } else {
        int t3 = (bid - 34816) * 256 + tid;       // [0, 32768) float4
        float4 z = {0.f, 0.f, 0.f, 0.f};
        if (t3 < 16384) ((float4*)logv)[t3] = z;  // logv+logq
        else ((float4*)out)[t3 - 16384] = z;      // out
    }
}

// ---------------- job-table GEMM ------------------------------------------
// NT GEMM: D[m][n] = sum_k A[m][k]*B[n][k], fp16 in, f32 accum, K%32==0.
// 64x128 tile (R11): 32-reg accumulator/wave -> 4 blocks/CU, +33% waves for
// latency hiding; A-stage bytes halve per block (less L2 staging traffic).
// Double-buffered LDS, raw s_barrier + vmcnt(3) prefetch wait (3 DMAs/stage).
// swz >= 0: z-batched XCD cluster (tiles/z = 1<<swz share bid%8).
// swz == -2: single-batch XCD cluster; gxl = log2(by-tiles per XCD).
// modes: 0 = f16 C; 1 = tanh -> C + staged C^T; 2 = C + staged C^T; 3 = logits.
struct Job {
    const f16* A; const f16* B;
    f16* Cout; f16* CTout;
    const f16* Sadd;
    const float* wvec;
    float* logits;
    long sA, sB, sC, sCT, sS, sL;
    int lda, ldb, ldc, ldct, ldsa;
    int mode, swz, gxl, K;
};
struct JobPack { Job j[3]; int end0, end1; };

__global__ __launch_bounds__(256, 4) void gemm_multi(JobPack jp) {
    int bid = blockIdx.x;
    int ji = (bid < jp.end0) ? 0 : ((bid < jp.end1) ? 1 : 2);
    const Job J = jp.j[ji];
    int local = bid - ((ji == 0) ? 0 : ((ji == 1) ? jp.end0 : jp.end1));

    int bx, by, bz;
    if (J.swz >= 0) {
        int tg = local >> 3;
        bz = (local & 7) + 8 * (tg >> J.swz);
        int t = tg & ((1 << J.swz) - 1);
        bx = t & ((1 << J.gxl) - 1);
        by = t >> J.gxl;
    } else {  // -2: single batch; gxl = log2(by per xcd)
        bz = 0;
        int x = local & 7, u = local >> 3;
        bx = u >> J.gxl;
        by = (x << J.gxl) | (u & ((1 << J.gxl) - 1));
    }

    const f16* Ab = J.A + (long)bz * J.sA;
    const f16* Bb = J.B + (long)bz * J.sB;
    int m0 = by * BM;
    int n0 = bx * BN;
    int tid = threadIdx.x;
    int wave = tid >> 6, lane = tid & 63;
    int quad = lane >> 4, l16 = lane & 15;
    int wm = (wave >> 1) * 32, wn = (wave & 1) * 64;

    // LDS: 2 x (As 4K + Bs 8K) = 24KB double buffer; epilogue T (18KB) overlays.
    __shared__ __align__(16) char smem[24576];
    f16* T = (f16*)smem;

    f32x4 zero = {0.f, 0.f, 0.f, 0.f};
    f32x4 acc[2][4];
#pragma unroll
    for (int i = 0; i < 2; i++)
#pragma unroll
        for (int j = 0; j < 4; j++) acc[i][j] = zero;

    int lda = J.lda, ldb = J.ldb;
    auto stage = [&](int buf, int k0) {
        f16* As = (f16*)(smem + buf * 12288);
        f16* Bs = (f16*)(smem + buf * 12288 + 4096);
        {   // A: 64 rows in one sweep (16 rows/wave)
            int rbase = wave * 16;
            int r = rbase + (lane >> 2);
            int sw = ((lane & 3) ^ ((r >> 1) & 3)) << 3;
            ld16(Ab + (long)(m0 + r) * lda + k0 + sw, As + rbase * 32);
        }
#pragma unroll
        for (int j = 0; j < 2; j++) {  // B: 128 rows (32 rows/wave)
            int rbase = wave * 32 + j * 16;
            int r = rbase + (lane >> 2);
            int sw = ((lane & 3) ^ ((r >> 1) & 3)) << 3;
            ld16(Bb + (long)(n0 + r) * ldb + k0 + sw, Bs + rbase * 32);
        }
    };

    const int NK = J.K >> 5;
    stage(0, 0);
    for (int ki = 0; ki < NK; ki++) {
        int cur = ki & 1;
        __builtin_amdgcn_s_barrier();           // buf[1-cur] readers done
        asm volatile("" ::: "memory");
        if (ki + 1 < NK) {
            stage(1 - cur, (ki + 1) << 5);
            __builtin_amdgcn_s_waitcnt(0xF73);  // vmcnt(3): tile-ki DMAs done
        } else {
            __builtin_amdgcn_s_waitcnt(0xF70);  // vmcnt(0)
        }
        __builtin_amdgcn_s_barrier();           // tile-ki visible to all
        asm volatile("" ::: "memory");

        const f16* As = (const f16*)(smem + cur * 12288);
        const f16* Bs = (const f16*)(smem + cur * 12288 + 4096);
        f16x8 af[2], bfr[4];
#pragma unroll
        for (int mt = 0; mt < 2; mt++) {
            int row = wm + mt * 16 + l16;
            af[mt] = *(const f16x8*)(As + row * 32 + ((quad ^ ((row >> 1) & 3)) << 3));
        }
#pragma unroll
        for (int nt = 0; nt < 4; nt++) {
            int row = wn + nt * 16 + l16;
            bfr[nt] = *(const f16x8*)(Bs + row * 32 + ((quad ^ ((row >> 1) & 3)) << 3));
        }
#pragma unroll
        for (int mt = 0; mt < 2; mt++)
#pragma unroll
            for (int nt = 0; nt < 4; nt++)
                acc[mt][nt] = __builtin_amdgcn_mfma_f32_16x16x32_f16(af[mt], bfr[nt], acc[mt][nt], 0, 0, 0);
        asm volatile("" ::: "memory");
    }

    int gmb = m0 + wm;
    int gnb = n0 + wn;

    if (J.mode == 3) {
        const f16* Sb = J.Sadd + (long)bz * J.sS;
        float* lg = J.logits + (long)bz * J.sL;
#pragma unroll
        for (int mt = 0; mt < 2; mt++) {
            int rowb = gmb + mt * 16 + quad * 4;
            float part[4] = {0.f, 0.f, 0.f, 0.f};
#pragma unroll
            for (int nt = 0; nt < 4; nt++) {
                int col = gnb + nt * 16 + l16;
                float w = J.wvec[col];
#pragma unroll
                for (int r = 0; r < 4; r++) {
                    float s = (float)Sb[(long)(rowb + r) * J.ldsa + col];
                    part[r] += fast_tanh(s + acc[mt][nt][r]) * w;
                }
            }
#pragma unroll
            for (int off = 1; off < 16; off <<= 1) {
#pragma unroll
                for (int r = 0; r < 4; r++) part[r] += __shfl_xor(part[r], off);
            }
            if (l16 == 0) {
#pragma unroll
                for (int r = 0; r < 4; r++) atomicAdd(&lg[rowb + r], part[r]);
            }
        }
        return;
    }

    // convert (and tanh for mode 1) ONCE into f16 regs; reuse for both stores
    f16x4 hreg[2][4];
#pragma unroll
    for (int mt = 0; mt < 2; mt++)
#pragma unroll
        for (int nt = 0; nt < 4; nt++) {
            float v0 = acc[mt][nt][0], v1 = acc[mt][nt][1];
            float v2 = acc[mt][nt][2], v3 = acc[mt][nt][3];
            if (J.mode == 1) {
                v0 = fast_tanh(v0); v1 = fast_tanh(v1);
                v2 = fast_tanh(v2); v3 = fast_tanh(v3);
            }
            f16x4 hv = {(f16)v0, (f16)v1, (f16)v2, (f16)v3};
            hreg[mt][nt] = hv;
        }

    f16* Cb = J.Cout + (long)bz * J.sC;
#pragma unroll
    for (int mt = 0; mt < 2; mt++) {
        int rowb = gmb + mt * 16 + quad * 4;
#pragma unroll
        for (int nt = 0; nt < 4; nt++) {
            int col = gnb + nt * 16 + l16;
#pragma unroll
            for (int r = 0; r < 4; r++)
                Cb[(long)(rowb + r) * J.ldc + col] = hreg[mt][nt][r];
        }
    }

    if (J.mode == 1 || J.mode == 2) {
        // staged transpose T[128][72] through LDS -> coalesced CT stores
        long bb = (J.mode == 2) ? (m0 >> 9) : bz;  // mode2: M-batched; mode1: z
        int lr0  = (J.mode == 2) ? (m0 & 511) : m0;
        f16* CTb = J.CTout + bb * J.sCT;
        __syncthreads();   // K-loop LDS reads fully done before T overlay
#pragma unroll
        for (int mt = 0; mt < 2; mt++) {
            int rloc = wm + mt * 16 + quad * 4;
#pragma unroll
            for (int nt = 0; nt < 4; nt++) {
                int cloc = wn + nt * 16 + l16;
                *(f16x4*)(T + cloc * 72 + rloc) = hreg[mt][nt];
            }
        }
        __syncthreads();
#pragma unroll
        for (int i = 0; i < 4; i++) {
            int id = tid + i * 256;         // [0,1024)
            int c = id >> 3, r8 = (id & 7) * 8;
            f16x8 v = *(const f16x8*)(T + c * 72 + r8);
            *(f16x8*)(CTb + (long)(n0 + c) * J.ldct + lr0 + r8) = v;
        }
    }
}

__device__ __forceinline__ float block_reduce(float v, float* red, int tid, bool is_max) {
#pragma unroll
    for (int off = 32; off >= 1; off >>= 1) {
        float o = __shfl_xor(v, off);
        v = is_max ? fmaxf(v, o) : (v + o);
    }
    if ((tid & 63) == 0) red[tid >> 6] = v;
    __syncthreads();
    float t = red[0];
#pragma unroll
    for (int i = 1; i < 8; i++) t = is_max ? fmaxf(t, red[i]) : (t + red[i]);
    __syncthreads();
    return t;
}

// grid (B, 2, 8): masked softmax over 512 logits (recomputed per z-slice),
// partial gather over 64 l's -> atomicAdd into out.
// use_h: gather from f16 copies (safe only with dedicated CT buffer).
__global__ __launch_bounds__(512) void softmax_gather(
    const float* __restrict__ logits_v, const float* __restrict__ logits_q,
    const int* __restrict__ mask1, const int* __restrict__ mask2,
    const float* __restrict__ s1f, const float* __restrict__ s2f,
    const f16* __restrict__ s1h, const f16* __restrict__ s2h, int use_h,
    float* __restrict__ out)
{
    int b = blockIdx.x;
    int which = blockIdx.y;
    int zp = blockIdx.z;
    const float* lg = (which ? logits_q : logits_v) + (long)b * 512;
    const int*   mk = (which ? mask2 : mask1) + (long)b * 512;
    float* o = out + (long)which * 64 * 512 + (long)b * 512;

    int tid = threadIdx.x;
    __shared__ float p[512];
    __shared__ float red[8];

    float m = (float)mk[tid];
    float x = lg[tid] * m;
    float mx = block_reduce(x, red, tid, true);
    float e = __expf(x - mx);
    float S1 = block_reduce(e, red, tid, false);
    float r = (e / S1) * m;
    float S2 = block_reduce(r, red, tid, false);
    p[tid] = r / (S2 + 1e-13f);
    __syncthreads();

    float acc = 0.f;
    int l0 = zp * 64;
    if (use_h) {
        const f16* S = (which ? s2h : s1h) + (long)b * 512 * 512;
#pragma unroll 8
        for (int l = l0; l < l0 + 64; l++) acc += p[l] * (float)S[(long)l * 512 + tid];
    } else {
        const float* S = (which ? s2f : s1f) + (long)b * 512 * 512;
#pragma unroll 8
        for (int l = l0; l < l0 + 64; l++) acc += p[l] * S[(long)l * 512 + tid];
    }
    atomicAdd(&o[tid], acc);
}

extern "C" void kernel_launch(void* const* d_in, const int* in_sizes, int n_in,
                              void* d_out, int out_size, void* d_ws, size_t ws_size,
                              hipStream_t stream) {
    const float* s1  = (const float*)d_in[0];
    const float* s2  = (const float*)d_in[1];
    const int* mask1 = (const int*)d_in[2];
    const int* mask2 = (const int*)d_in[3];
    const float* W   = (const float*)d_in[4];
    const float* Wv  = (const float*)d_in[5];
    const float* Wq  = (const float*)d_in[6];
    const float* whv = (const float*)d_in[7];
    const float* whq = (const float*)d_in[8];
    float* out = (float*)d_out;

    const long Bn = 64, L = 512, D = 512, Aa = 256;
    char* ws = (char*)d_ws;
    size_t off = 0;
    auto alloc = [&](size_t bytes) -> char* {
        char* p = ws + off;
        off += (bytes + 255) & ~(size_t)255;
        return p;
    };
    f16* s1b   = (f16*)alloc(Bn * L * D * 2);
    f16* s2b   = (f16*)alloc(Bn * L * D * 2);
    f16* s1W   = (f16*)alloc(Bn * L * D * 2);
    f16* Cb    = (f16*)alloc(Bn * L * L * 2);
    f16* s1Wv  = (f16*)alloc(Bn * L * Aa * 2);
    f16* s1WvT = (f16*)alloc(Bn * L * Aa * 2);
    f16* s2Wq  = (f16*)alloc(Bn * L * Aa * 2);
    f16* s2WqT = (f16*)alloc(Bn * L * Aa * 2);
    f16* WTb   = (f16*)alloc(D * D * 2);
    f16* WvTb  = (f16*)alloc(D * Aa * 2);
    f16* WqTb  = (f16*)alloc(D * Aa * 2);
    float* logv = (float*)alloc(2 * Bn * L * 4);
    float* logq = logv + Bn * L;
    size_t base_off = off;
    f16* CTded = (f16*)alloc(Bn * L * L * 2);  // dedicated CT if it fits
    if (ws_size < base_off) return;
    int use_ded = (ws_size >= off) ? 1 : 0;
    f16* CTb = use_ded ? CTded : s1b;  // fallback: alias (then f32 gather)

    // 1) prep: converts + transposes + zero logits/out
    prep<<<dim3(34944), 256, 0, stream>>>(s1, s2, s1b, s2b, W, Wv, Wq,
                                          WTb, WvTb, WqTb, logv, out);

    Job z0{};

    // 2) merged GEMM1 + GEMM3a + GEMM3b (4096 blocks, 64x128 tiles)
    {
        JobPack p{};
        Job& a = p.j[0];  // GEMM1: s1W = s1 @ W  (gx=4, gy=512)
        a.A = s1b; a.B = WTb; a.Cout = s1W;
        a.lda = 512; a.ldb = 512; a.ldc = 512; a.K = 512;
        a.mode = 0; a.swz = -2; a.gxl = 6;   // 64 by-tiles per XCD
        Job& b = p.j[1];  // GEMM3a: s1Wv(+T) = s1 @ Wv (gx=2, gy=512)
        b.A = s1b; b.B = WvTb; b.Cout = s1Wv; b.CTout = s1WvT;
        b.lda = 512; b.ldb = 512; b.ldc = 256; b.ldct = 512; b.sCT = L * Aa;
        b.K = 512; b.mode = 2; b.swz = -2; b.gxl = 6;
        Job& c = p.j[2];  // GEMM3b: s2Wq(+T) = s2 @ Wq
        c.A = s2b; c.B = WqTb; c.Cout = s2Wq; c.CTout = s2WqT;
        c.lda = 512; c.ldb = 512; c.ldc = 256; c.ldct = 512; c.sCT = L * Aa;
        c.K = 512; c.mode = 2; c.swz = -2; c.gxl = 6;
        p.end0 = 2048; p.end1 = 3072;
        gemm_multi<<<dim3(4096), 256, 0, stream>>>(p);
    }

    // 3) GEMM2 (2048 blocks, XCD-clustered 32 tiles/z): C = tanh(s1W @ s2^T) + C^T
    {
        JobPack p{};
        Job& a = p.j[0];
        a.A = s1W; a.B = s2b; a.Cout = Cb; a.CTout = CTb;
        a.lda = 512; a.ldb = 512; a.ldc = 512; a.ldct = 512;
        a.sA = L * D; a.sB = L * D; a.sC = L * L; a.sCT = L * L;
        a.K = 512; a.mode = 1; a.swz = 5; a.gxl = 2;
        p.j[1] = z0; p.j[2] = z0;
        p.end0 = 2048; p.end1 = 2048;
        gemm_multi<<<dim3(2048), 256, 0, stream>>>(p);
    }

    // 4) merged GEMM4a + GEMM4b (2048 blocks, XCD-clustered 16 tiles/z)
    {
        JobPack p{};
        Job& a = p.j[0];  // logits_v += rowsum tanh(s1Wv + C @ s2Wq) * whv
        a.A = Cb; a.B = s2WqT; a.Sadd = s1Wv; a.wvec = whv; a.logits = logv;
        a.lda = 512; a.ldb = 512; a.ldsa = 256;
        a.sA = L * L; a.sB = Aa * L; a.sS = L * Aa; a.sL = 512;
        a.K = 512; a.mode = 3; a.swz = 4; a.gxl = 1;
        Job& b = p.j[1];  // logits_q += rowsum tanh(s2Wq + C^T @ s1Wv) * whq
        b.A = CTb; b.B = s1WvT; b.Sadd = s2Wq; b.wvec = whq; b.logits = logq;
        b.lda = 512; b.ldb = 512; b.ldsa = 256;
        b.sA = L * L; b.sB = Aa * L; b.sS = L * Aa; b.sL = 512;
        b.K = 512; b.mode = 3; b.swz = 4; b.gxl = 1;
        p.j[2] = z0;
        p.end0 = 1024; p.end1 = 2048;
        gemm_multi<<<dim3(2048), 256, 0, stream>>>(p);
    }

    // 5) masked softmax + weighted gather (f16 inputs when CT is dedicated)
    softmax_gather<<<dim3((int)Bn, 2, 8), 512, 0, stream>>>(
        logv, logq, mask1, mask2, s1, s2, s1b, s2b, use_ded, out);
}